// Round 14
// baseline (260.906 us; speedup 1.0000x reference)
//
#include <hip/hip_runtime.h>
#include <hip/hip_bf16.h>
#include <math.h>

// Problem constants
#define HIDDEN 1024
#define HEADS  16
#define HDIM   64
#define BATCH  2
#define SEQ    2048
#define ROWS   (BATCH*SEQ)   // 4096
#define BH     (BATCH*HEADS) // 32

typedef __attribute__((ext_vector_type(8))) short  short8;
typedef __attribute__((ext_vector_type(8))) __bf16 bf16x8;
typedef __attribute__((ext_vector_type(4))) float  f32x4;

static __device__ __forceinline__ unsigned short f2bf(float f) {
    unsigned int u = __builtin_bit_cast(unsigned int, f);
    u += 0x7FFFu + ((u >> 16) & 1u);   // round-to-nearest-even
    return (unsigned short)(u >> 16);
}
static __device__ __forceinline__ float bf2f(unsigned short h) {
    unsigned int u = ((unsigned int)h) << 16;
    return __builtin_bit_cast(float, u);
}
static __device__ __forceinline__ f32x4 mfma16(short8 a, short8 b, f32x4 c) {
    return __builtin_amdgcn_mfma_f32_16x16x32_bf16(
        __builtin_bit_cast(bf16x8, a), __builtin_bit_cast(bf16x8, b), c, 0, 0, 0);
}
// async global->LDS, 16B per lane; lds dest = wave-uniform base + lane*16
static __device__ __forceinline__ void gl_lds16(const unsigned short* g, unsigned short* l) {
    __builtin_amdgcn_global_load_lds(
        (const __attribute__((address_space(1))) unsigned int*)g,
        (__attribute__((address_space(3))) unsigned int*)l, 16, 0, 0);
}

// ---------------------------------------------------------------- x -> bf16 (+ prep folded in)
__global__ void convert_x_kernel(const float* __restrict__ x, unsigned short* __restrict__ xb,
                                 const float* __restrict__ qp, const float* __restrict__ qa,
                                 float* __restrict__ mod, float* __restrict__ mod2,
                                 float* __restrict__ posc, float* __restrict__ poss) {
    int i = (blockIdx.x * 256 + threadIdx.x) * 4;
    float4 v = *(const float4*)(x + i);
    ushort4 o;
    o.x = f2bf(v.x); o.y = f2bf(v.y); o.z = f2bf(v.z); o.w = f2bf(v.w);
    *(ushort4*)(xb + i) = o;
    if (blockIdx.x < 8) {
        int k = blockIdx.x * 256 + threadIdx.x;
        if (k < HIDDEN) {
            float m = cosf(qp[k]) * qa[k];
            mod[k] = m;
            mod2[k] = m * m * 0.18033688011112042f;   // mod^2 * 0.125 * log2(e)
        }
        if (k < SEQ) {
            float ang = (float)k * (6.283185307179586f / (float)SEQ);
            posc[k] = cosf(ang);
            poss[k] = sinf(ang);
        }
    }
}

// ---------------------------------------------------------------- W -> bf16 transposed  Wt[n][k] = W[k][n]
__global__ __launch_bounds__(256) void transpose_w_kernel(
    const float* __restrict__ w0, const float* __restrict__ w1,
    const float* __restrict__ w2, const float* __restrict__ w3,
    unsigned short* __restrict__ wt) {
    __shared__ unsigned short tile[64][72];
    const float* src = (blockIdx.z == 0) ? w0 : (blockIdx.z == 1) ? w1 : (blockIdx.z == 2) ? w2 : w3;
    unsigned short* dst = wt + (size_t)blockIdx.z * HIDDEN * HIDDEN;
    int n0 = blockIdx.x * 64, k0 = blockIdx.y * 64;
    int t = threadIdx.x;
    int cg = t & 15, r0 = t >> 4;
#pragma unroll
    for (int rr = 0; rr < 4; rr++) {
        int kl = r0 + rr * 16;
        float4 v = *(const float4*)(src + (size_t)(k0 + kl) * HIDDEN + n0 + cg * 4);
        tile[cg*4+0][kl] = f2bf(v.x);
        tile[cg*4+1][kl] = f2bf(v.y);
        tile[cg*4+2][kl] = f2bf(v.z);
        tile[cg*4+3][kl] = f2bf(v.w);
    }
    __syncthreads();
#pragma unroll
    for (int rr = 0; rr < 4; rr++) {
        int nl = r0 + rr * 16;
        ushort4 o;
        o.x = tile[nl][cg*4+0]; o.y = tile[nl][cg*4+1];
        o.z = tile[nl][cg*4+2]; o.w = tile[nl][cg*4+3];
        *(ushort4*)(dst + (size_t)(n0 + nl) * HIDDEN + k0 + cg * 4) = o;
    }
}

// ---------------------------------------------------------------- GEMM v2: 64x128 tile, BK=32,
// single-barrier double-buffered async staging (attn-proven K-loop shape).
// LDS 24 KB -> ~6 blocks/CU; acc 32 VGPR/wave. XOR swizzle: LDS[r][c] = G[r][c^(r&3)]
// (chunk = 8 shorts); read chunk quad^(l15&3) -> 2-way max banks.
// grid = (mtiles=64, ntiles=8, z): flat id % 8 = mtile % 8 -> m-panel pinned to one XCD.
__global__ __launch_bounds__(256) void gemm_kernel(
    const unsigned short* __restrict__ A, const unsigned short* __restrict__ WtBase,
    unsigned short* __restrict__ CBase, float* __restrict__ Out, int mode0) {
    __shared__ unsigned short Alds[2][64 * 32];    // 2 x 4 KB
    __shared__ unsigned short Blds[2][128 * 32];   // 2 x 8 KB
    const int mode = mode0 + blockIdx.z;
    const unsigned short* Bt = WtBase + (size_t)mode * HIDDEN * HIDDEN;
    unsigned short* Cout = CBase + (size_t)mode * ROWS * HIDDEN;
    const int m0 = blockIdx.x * 64, n0 = blockIdx.y * 128;
    const int tid = threadIdx.x;
    const int wave = tid >> 6, lane = tid & 63, quad = lane >> 4, l15 = lane & 15;
    const int wr = wave >> 1, wc = wave & 1;
    const int srow4 = lane >> 2;                   // 0..15 (row within 16-row segment)
    const int schunk = (lane & 3) ^ (srow4 & 3);   // swizzled source chunk
    const int rchunk = quad ^ (l15 & 3);           // swizzled read chunk

    f32x4 acc[2][4];
    const f32x4 z4 = {0.f, 0.f, 0.f, 0.f};
#pragma unroll
    for (int i = 0; i < 2; i++)
#pragma unroll
        for (int j = 0; j < 4; j++) acc[i][j] = z4;

    auto stage = [&](int k0, int buf) {
        {   // A: 64 rows x 32 shorts = 4 KB, one instr (16 rows/wave)
            int rb = wave * 16;
            gl_lds16(A + (size_t)(m0 + rb + srow4) * HIDDEN + k0 + schunk * 8,
                     &Alds[buf][rb * 32]);
        }
#pragma unroll
        for (int p = 0; p < 2; p++) {   // B: 128 rows, 2 instr
            int rb = p * 64 + wave * 16;
            gl_lds16(Bt + (size_t)(n0 + rb + srow4) * HIDDEN + k0 + schunk * 8,
                     &Blds[buf][rb * 32]);
        }
    };

    stage(0, 0);
    for (int it = 0; it < HIDDEN / 32; it++) {
        __syncthreads();                                   // stage(it) landed; buf (it-1) free
        if (it + 1 < HIDDEN / 32) stage((it + 1) * 32, (it + 1) & 1);
        const int buf = it & 1;
        short8 aF[2], bF[4];
#pragma unroll
        for (int i = 0; i < 2; i++)
            aF[i] = *(const short8*)(&Alds[buf][(wr * 32 + i * 16 + l15) * 32 + rchunk * 8]);
#pragma unroll
        for (int j = 0; j < 4; j++)
            bF[j] = *(const short8*)(&Blds[buf][(wc * 64 + j * 16 + l15) * 32 + rchunk * 8]);
#pragma unroll
        for (int i = 0; i < 2; i++)
#pragma unroll
            for (int j = 0; j < 4; j++)
                acc[i][j] = mfma16(aF[i], bF[j], acc[i][j]);
    }

#pragma unroll
    for (int i = 0; i < 2; i++) {
        int mbase = m0 + wr * 32 + i * 16 + quad * 4;
#pragma unroll
        for (int j = 0; j < 4; j++) {
            int n = n0 + wc * 64 + j * 16 + l15;
#pragma unroll
            for (int r = 0; r < 4; r++) {
                float val = acc[i][j][r];
                int mm = mbase + r;
                if (mode == 3) Out[(size_t)mm * HIDDEN + n] = val;
                else           Cout[(size_t)mm * HIDDEN + n] = f2bf(val);
            }
        }
    }
}

// ---------------------------------------------------------------- V: mod + shift + transpose
// Vpt[bh][d][s] = (Vm[s][d] + Vm[(s+1)%S][d])/sqrt2, Vm = Cv*mod. grid = (bh=32, stile=32).
__global__ __launch_bounds__(256) void vmod_shift(const unsigned short* __restrict__ Cv,
                                                  unsigned short* __restrict__ Vpt,
                                                  const float* __restrict__ mod) {
    __shared__ unsigned short lds[65][72];
    int bh = blockIdx.x, b = bh >> 4, h = bh & 15;
    int s0 = blockIdx.y * 64;
    int t = threadIdx.x;
    int cg = t & 15, r0 = t >> 4;
    const float4 m4 = *(const float4*)(mod + h * 64 + cg * 4);
#pragma unroll
    for (int rr = 0; rr < 4; rr++) {
        int row = r0 + rr * 16;
        ushort4 v = *(const ushort4*)(Cv + ((size_t)(b * SEQ + s0 + row)) * HIDDEN + h * 64 + cg * 4);
        lds[row][cg*4+0] = f2bf(bf2f(v.x) * m4.x);
        lds[row][cg*4+1] = f2bf(bf2f(v.y) * m4.y);
        lds[row][cg*4+2] = f2bf(bf2f(v.z) * m4.z);
        lds[row][cg*4+3] = f2bf(bf2f(v.w) * m4.w);
    }
    if (t < 16) {
        int srow = (s0 + 64) & (SEQ - 1);
        const float4 mm4 = *(const float4*)(mod + h * 64 + t * 4);
        ushort4 v = *(const ushort4*)(Cv + ((size_t)(b * SEQ + srow)) * HIDDEN + h * 64 + t * 4);
        lds[64][t*4+0] = f2bf(bf2f(v.x) * mm4.x);
        lds[64][t*4+1] = f2bf(bf2f(v.y) * mm4.y);
        lds[64][t*4+2] = f2bf(bf2f(v.z) * mm4.z);
        lds[64][t*4+3] = f2bf(bf2f(v.w) * mm4.w);
    }
    __syncthreads();
    int d = t & 63, sb = (t >> 6) * 16;
    unsigned short outv[16];
#pragma unroll
    for (int k = 0; k < 16; k++) {
        float a = bf2f(lds[sb + k][d]), bb = bf2f(lds[sb + k + 1][d]);
        outv[k] = f2bf((a + bb) * 0.7071067811865476f);
    }
    unsigned short* dst = Vpt + ((size_t)bh * 64 + d) * SEQ + s0 + sb;
#pragma unroll
    for (int k = 0; k < 16; k += 4) {
        ushort4 o; o.x = outv[k]; o.y = outv[k+1]; o.z = outv[k+2]; o.w = outv[k+3];
        *(ushort4*)(dst + k) = o;
    }
}

// ---------------------------------------------------------------- flash attention (unchanged R12)
#define KT 64
#define PSTR 76    // P row stride: quad bank offsets {0,24,16,8} -> <=2-way
__global__ __launch_bounds__(256) void attn_kernel(const unsigned short* __restrict__ Cq,
                                                   const unsigned short* __restrict__ Ck,
                                                   const unsigned short* __restrict__ Vpt,
                                                   unsigned short* __restrict__ Ob,
                                                   const float* __restrict__ mod2,
                                                   const float* __restrict__ posc,
                                                   const float* __restrict__ poss) {
    __shared__ unsigned short Klds[2][KT * 64];      // 2 x 8 KB, unpadded
    __shared__ unsigned short Vtlds[2][64 * 64];     // 2 x 8 KB, unpadded
    __shared__ unsigned short Plds[4 * 32 * PSTR];   // 19456 B
    const int bh = blockIdx.x;
    const int b = bh >> 4, h = bh & 15;
    const int tid = threadIdx.x, wave = tid >> 6, lane = tid & 63;
    const int quad = lane >> 4, l15 = lane & 15;
    const int q0 = blockIdx.y * 128 + wave * 32;

    // Q fragments (D=64): q'_d = Cq_d * mod2_d
    short8 qf[2][2];
#pragma unroll
    for (int g = 0; g < 2; g++) {
        int ss = q0 + g * 16 + l15;
        const unsigned short* crow = Cq + ((size_t)(b * SEQ + ss)) * HIDDEN + h * 64;
#pragma unroll
        for (int kk = 0; kk < 2; kk++) {
            int bd = kk * 32 + quad * 8;
            short8 u = *(const short8*)(crow + bd);
            short8 q;
#pragma unroll
            for (int e = 0; e < 8; e++)
                q[e] = (short)f2bf(bf2f((unsigned short)u[e]) * mod2[h * 64 + bd + e]);
            qf[g][kk] = q;
        }
    }
    // per-q-row interference factors
    float ci[2][4], si[2][4];
#pragma unroll
    for (int g = 0; g < 2; g++)
#pragma unroll
        for (int r = 0; r < 4; r++) {
            int ss = q0 + g * 16 + quad * 4 + r;
            ci[g][r] = posc[ss];
            si[g][r] = poss[ss];
        }

    short8 ones;
#pragma unroll
    for (int e = 0; e < 8; e++) ones[e] = (short)0x3F80;

    const f32x4 z4 = {0.f, 0.f, 0.f, 0.f};
    f32x4 acc[2][4], accden[2];
#pragma unroll
    for (int g = 0; g < 2; g++) {
#pragma unroll
        for (int dt = 0; dt < 4; dt++) acc[g][dt] = z4;
        accden[g] = z4;
    }

    unsigned short* pw = &Plds[wave * 32 * PSTR];

    const unsigned short* Kbh = Ck  + ((size_t)b * SEQ) * HIDDEN + h * 64;  // row stride HIDDEN
    const unsigned short* Vbh = Vpt + (size_t)bh * 64 * SEQ;

    auto stage = [&](int j, int buf) {
#pragma unroll
        for (int p = 0; p < 2; p++) {               // K: 64 rows x 64 shorts
            int rb = p * 32 + wave * 8;
            int r  = rb + (lane >> 3);
            int c  = (lane & 7) ^ (r & 7);
            gl_lds16(Kbh + (size_t)(j + r) * HIDDEN + c * 8, &Klds[buf][rb * 64]);
        }
#pragma unroll
        for (int p = 0; p < 2; p++) {               // V^T: 2 passes of 32 d-rows
            int rb = p * 32 + wave * 8;
            int r  = rb + (lane >> 3);
            int c  = (lane & 7) ^ (r & 7);
            gl_lds16(Vbh + (size_t)r * SEQ + j + c * 8, &Vtlds[buf][rb * 64]);
        }
    };

    float cjc[4], sjc[4];
#pragma unroll
    for (int t2 = 0; t2 < 4; t2++) {
        int jj = t2 * 16 + l15;
        cjc[t2] = posc[jj]; sjc[t2] = poss[jj];
    }

    stage(0, 0);
    for (int it = 0; it < SEQ / KT; it++) {
        __syncthreads();
        float cjn[4] = {0.f, 0.f, 0.f, 0.f}, sjn[4] = {0.f, 0.f, 0.f, 0.f};
        if (it + 1 < SEQ / KT) {
            stage((it + 1) * KT, (it + 1) & 1);
#pragma unroll
            for (int t2 = 0; t2 < 4; t2++) {
                int jj = (it + 1) * KT + t2 * 16 + l15;
                cjn[t2] = posc[jj]; sjn[t2] = poss[jj];
            }
        }
        const int buf = it & 1;

#pragma unroll
        for (int t2 = 0; t2 < 4; t2++) {
            float cj = cjc[t2], sj = sjc[t2];
            f32x4 sc[2] = {z4, z4};
#pragma unroll
            for (int kk = 0; kk < 2; kk++) {
                int ch = (kk * 4 + quad) ^ (l15 & 7);
                short8 kf = *(const short8*)(&Klds[buf][(t2 * 16 + l15) * 64 + ch * 8]);
#pragma unroll
                for (int g = 0; g < 2; g++)
                    sc[g] = mfma16(qf[g][kk], kf, sc[g]);
            }
#pragma unroll
            for (int g = 0; g < 2; g++) {
#pragma unroll
                for (int r = 0; r < 4; r++) {
                    float w = ci[g][r] * cj + si[g][r] * sj;
                    float p = __builtin_amdgcn_exp2f(sc[g][r] * w);
                    unsigned short pt = (unsigned short)(__builtin_bit_cast(unsigned int, p) >> 16);
                    pw[(g * 16 + quad * 4 + r) * PSTR + t2 * 16 + l15] = pt;
                }
            }
        }

#pragma unroll
        for (int pt = 0; pt < 2; pt++) {
            short8 pa0 = *(const short8*)(&pw[(l15) * PSTR + pt * 32 + quad * 8]);
            short8 pa1 = *(const short8*)(&pw[(16 + l15) * PSTR + pt * 32 + quad * 8]);
            accden[0] = mfma16(pa0, ones, accden[0]);
            accden[1] = mfma16(pa1, ones, accden[1]);
#pragma unroll
            for (int dt = 0; dt < 4; dt++) {
                int ch = (pt * 4 + quad) ^ (l15 & 7);
                short8 vb = *(const short8*)(&Vtlds[buf][(dt * 16 + l15) * 64 + ch * 8]);
                acc[0][dt] = mfma16(pa0, vb, acc[0][dt]);
                acc[1][dt] = mfma16(pa1, vb, acc[1][dt]);
            }
        }
#pragma unroll
        for (int t2 = 0; t2 < 4; t2++) { cjc[t2] = cjn[t2]; sjc[t2] = sjn[t2]; }
    }

#pragma unroll
    for (int g = 0; g < 2; g++) {
        float rinv[4];
#pragma unroll
        for (int r = 0; r < 4; r++) rinv[r] = 1.0f / accden[g][r];
#pragma unroll
        for (int dt = 0; dt < 4; dt++) {
#pragma unroll
            for (int r = 0; r < 4; r++) {
                int q = q0 + g * 16 + quad * 4 + r;
                int d = dt * 16 + l15;
                Ob[((size_t)(b * SEQ + q)) * HIDDEN + h * 64 + d] = f2bf(acc[g][dt][r] * rinv[r]);
            }
        }
    }
}

// ---------------------------------------------------------------- launch
extern "C" void kernel_launch(void* const* d_in, const int* in_sizes, int n_in,
                              void* d_out, int out_size, void* d_ws, size_t ws_size,
                              hipStream_t stream) {
    const float* x  = (const float*)d_in[0];
    const float* Wq = (const float*)d_in[1];
    const float* Wk = (const float*)d_in[2];
    const float* Wv = (const float*)d_in[3];
    const float* Wo = (const float*)d_in[4];
    const float* qp = (const float*)d_in[5];
    const float* qa = (const float*)d_in[6];
    char* ws = (char*)d_ws;

    unsigned short* Xb  = (unsigned short*)(ws);                      // 8 MB (reused as Ob)
    unsigned short* Wt  = (unsigned short*)(ws + (size_t)( 8 << 20)); // 8 MB (4 x 2MB)
    unsigned short* Cq  = (unsigned short*)(ws + (size_t)(16 << 20)); // 8 MB
    unsigned short* Ck  = (unsigned short*)(ws + (size_t)(24 << 20)); // 8 MB
    unsigned short* Cv  = (unsigned short*)(ws + (size_t)(32 << 20)); // 8 MB
    unsigned short* Vpt = (unsigned short*)(ws + (size_t)(40 << 20)); // 8 MB
    float* mod  = (float*)(ws + (size_t)(48 << 20));
    float* mod2 = mod + 1024;
    float* posc = mod2 + 1024;
    float* poss = posc + 2048;
    float* out  = (float*)d_out;

    convert_x_kernel<<<4096, 256, 0, stream>>>(x, Xb, qp, qa, mod, mod2, posc, poss);
    transpose_w_kernel<<<dim3(16, 16, 4), 256, 0, stream>>>(Wq, Wk, Wv, Wo, Wt);
    gemm_kernel<<<dim3(64, 8, 3), 256, 0, stream>>>(Xb, Wt, Cq, out, 0);   // -> Cq,Ck,Cv
    vmod_shift<<<dim3(32, 32), 256, 0, stream>>>(Cv, Vpt, mod);
    attn_kernel<<<dim3(32, 16), 256, 0, stream>>>(Cq, Ck, Vpt, Xb /*Ob*/, mod2, posc, poss);
    gemm_kernel<<<dim3(64, 8, 1), 256, 0, stream>>>(Xb, Wt, Cq, out, 3);   // O-proj -> out
}

// Round 15
// 246.234 us; speedup vs baseline: 1.0596x; 1.0596x over previous
//
#include <hip/hip_runtime.h>
#include <hip/hip_bf16.h>
#include <math.h>

// Problem constants
#define HIDDEN 1024
#define HEADS  16
#define HDIM   64
#define BATCH  2
#define SEQ    2048
#define ROWS   (BATCH*SEQ)   // 4096
#define BH     (BATCH*HEADS) // 32

typedef __attribute__((ext_vector_type(8))) short  short8;
typedef __attribute__((ext_vector_type(8))) __bf16 bf16x8;
typedef __attribute__((ext_vector_type(4))) float  f32x4;

static __device__ __forceinline__ unsigned short f2bf(float f) {
    unsigned int u = __builtin_bit_cast(unsigned int, f);
    u += 0x7FFFu + ((u >> 16) & 1u);   // round-to-nearest-even
    return (unsigned short)(u >> 16);
}
static __device__ __forceinline__ float bf2f(unsigned short h) {
    unsigned int u = ((unsigned int)h) << 16;
    return __builtin_bit_cast(float, u);
}
static __device__ __forceinline__ f32x4 mfma16(short8 a, short8 b, f32x4 c) {
    return __builtin_amdgcn_mfma_f32_16x16x32_bf16(
        __builtin_bit_cast(bf16x8, a), __builtin_bit_cast(bf16x8, b), c, 0, 0, 0);
}
// async global->LDS, 16B per lane; lds dest = wave-uniform base + lane*16
static __device__ __forceinline__ void gl_lds16(const unsigned short* g, unsigned short* l) {
    __builtin_amdgcn_global_load_lds(
        (const __attribute__((address_space(1))) unsigned int*)g,
        (__attribute__((address_space(3))) unsigned int*)l, 16, 0, 0);
}

// ---------------------------------------------------------------- prep: x->bf16 + W->bf16^T + consts
// grid 5120: blocks [0,4096) convert x (+ mod/pos tables in first 8); [4096,5120) transpose W.
__global__ __launch_bounds__(256) void prep_kernel(
    const float* __restrict__ x, unsigned short* __restrict__ xb,
    const float* __restrict__ w0, const float* __restrict__ w1,
    const float* __restrict__ w2, const float* __restrict__ w3,
    unsigned short* __restrict__ wt,
    const float* __restrict__ qp, const float* __restrict__ qa,
    float* __restrict__ mod, float* __restrict__ mod2,
    float* __restrict__ posc, float* __restrict__ poss) {
    __shared__ unsigned short tile[64][72];
    const int bid = blockIdx.x;
    const int t = threadIdx.x;
    if (bid < 4096) {
        int i = (bid * 256 + t) * 4;
        float4 v = *(const float4*)(x + i);
        ushort4 o;
        o.x = f2bf(v.x); o.y = f2bf(v.y); o.z = f2bf(v.z); o.w = f2bf(v.w);
        *(ushort4*)(xb + i) = o;
        if (bid < 8) {
            int k = bid * 256 + t;
            if (k < HIDDEN) {
                float m = cosf(qp[k]) * qa[k];
                mod[k] = m;
                mod2[k] = m * m * 0.18033688011112042f;   // mod^2 * 0.125 * log2(e)
            }
            if (k < SEQ) {
                float ang = (float)k * (6.283185307179586f / (float)SEQ);
                posc[k] = cosf(ang);
                poss[k] = sinf(ang);
            }
        }
        return;
    }
    int rem = bid - 4096;
    int z = rem >> 8, r2 = rem & 255;
    int n0 = (r2 & 15) * 64, k0 = (r2 >> 4) * 64;
    const float* src = (z == 0) ? w0 : (z == 1) ? w1 : (z == 2) ? w2 : w3;
    unsigned short* dst = wt + (size_t)z * HIDDEN * HIDDEN;
    int cg = t & 15, r0 = t >> 4;
#pragma unroll
    for (int rr = 0; rr < 4; rr++) {
        int kl = r0 + rr * 16;
        float4 v = *(const float4*)(src + (size_t)(k0 + kl) * HIDDEN + n0 + cg * 4);
        tile[cg*4+0][kl] = f2bf(v.x);
        tile[cg*4+1][kl] = f2bf(v.y);
        tile[cg*4+2][kl] = f2bf(v.z);
        tile[cg*4+3][kl] = f2bf(v.w);
    }
    __syncthreads();
#pragma unroll
    for (int rr = 0; rr < 4; rr++) {
        int nl = r0 + rr * 16;
        ushort4 o;
        o.x = tile[nl][cg*4+0]; o.y = tile[nl][cg*4+1];
        o.z = tile[nl][cg*4+2]; o.w = tile[nl][cg*4+3];
        *(ushort4*)(dst + (size_t)(n0 + nl) * HIDDEN + k0 + cg * 4) = o;
    }
}

// ---------------------------------------------------------------- GEMM QKV (R12: 128x128, BK=64, XOR swizzle)
// mode 0/1: plain bf16 C. mode 2: C*mod (V-mod folded). grid (32,8,3): id%8 -> XCD-pinned m-panel.
__global__ __launch_bounds__(256) void gemm_kernel(
    const unsigned short* __restrict__ A, const unsigned short* __restrict__ WtBase,
    unsigned short* __restrict__ CBase, const float* __restrict__ mod) {
    __shared__ unsigned short Alds[128 * 64];   // 16 KB
    __shared__ unsigned short Blds[128 * 64];   // 16 KB
    const int mode = blockIdx.z;
    const unsigned short* Bt = WtBase + (size_t)mode * HIDDEN * HIDDEN;
    unsigned short* Cout = CBase + (size_t)mode * ROWS * HIDDEN;
    const int m0 = blockIdx.x * 128, n0 = blockIdx.y * 128;
    const int tid = threadIdx.x;
    const int wave = tid >> 6, lane = tid & 63, quad = lane >> 4, l15 = lane & 15;
    const int wr = wave >> 1, wc = wave & 1;
    const int srow = lane >> 3;
    const int schunk = (lane & 7) ^ (srow & 7);          // swizzled source chunk

    f32x4 acc[4][4];
    const f32x4 z4 = {0.f, 0.f, 0.f, 0.f};
#pragma unroll
    for (int i = 0; i < 4; i++)
#pragma unroll
        for (int j = 0; j < 4; j++) acc[i][j] = z4;

    for (int k0 = 0; k0 < HIDDEN; k0 += 64) {
#pragma unroll
        for (int p = 0; p < 4; p++) {
            int rbase = p * 32 + wave * 8;
            gl_lds16(A  + (size_t)(m0 + rbase + srow) * HIDDEN + k0 + schunk * 8,
                     &Alds[rbase * 64]);
            gl_lds16(Bt + (size_t)(n0 + rbase + srow) * HIDDEN + k0 + schunk * 8,
                     &Blds[rbase * 64]);
        }
        __syncthreads();
        short8 aF[4][2], bF[4][2];
#pragma unroll
        for (int h = 0; h < 2; h++) {
#pragma unroll
            for (int i = 0; i < 4; i++) {
                int row = wr * 64 + i * 16 + l15;
                aF[i][h] = *(const short8*)(&Alds[row * 64 + ((h * 4 + quad) ^ (l15 & 7)) * 8]);
            }
#pragma unroll
            for (int j = 0; j < 4; j++) {
                int row = wc * 64 + j * 16 + l15;
                bF[j][h] = *(const short8*)(&Blds[row * 64 + ((h * 4 + quad) ^ (l15 & 7)) * 8]);
            }
        }
#pragma unroll
        for (int h = 0; h < 2; h++)
#pragma unroll
            for (int i = 0; i < 4; i++)
#pragma unroll
                for (int j = 0; j < 4; j++)
                    acc[i][j] = mfma16(aF[i][h], bF[j][h], acc[i][j]);
        __syncthreads();
    }

#pragma unroll
    for (int i = 0; i < 4; i++) {
        int mbase = m0 + wr * 64 + i * 16 + quad * 4;
#pragma unroll
        for (int j = 0; j < 4; j++) {
            int n = n0 + wc * 64 + j * 16 + l15;
            float vm = (mode == 2) ? mod[n] : 1.0f;
#pragma unroll
            for (int r = 0; r < 4; r++) {
                int mm = mbase + r;
                Cout[(size_t)mm * HIDDEN + n] = f2bf(acc[i][j][r] * vm);
            }
        }
    }
}

// ---------------------------------------------------------------- GEMM O: 128x64 tile, BK=64
// grid (32,16) = 512 blocks = 2/CU (vs 1/CU at 128x128). fp32 out. id%8 -> XCD-pinned m-panel.
__global__ __launch_bounds__(256) void gemm_o_kernel(
    const unsigned short* __restrict__ A, const unsigned short* __restrict__ Bt,
    float* __restrict__ Out) {
    __shared__ unsigned short Alds[128 * 64];   // 16 KB
    __shared__ unsigned short Blds[64 * 64];    // 8 KB
    const int m0 = blockIdx.x * 128, n0 = blockIdx.y * 64;
    const int tid = threadIdx.x;
    const int wave = tid >> 6, lane = tid & 63, quad = lane >> 4, l15 = lane & 15;
    const int wr = wave >> 1, wc = wave & 1;
    const int srow = lane >> 3;
    const int schunk = (lane & 7) ^ (srow & 7);

    f32x4 acc[4][2];
    const f32x4 z4 = {0.f, 0.f, 0.f, 0.f};
#pragma unroll
    for (int i = 0; i < 4; i++)
#pragma unroll
        for (int j = 0; j < 2; j++) acc[i][j] = z4;

    for (int k0 = 0; k0 < HIDDEN; k0 += 64) {
#pragma unroll
        for (int p = 0; p < 4; p++) {
            int rbase = p * 32 + wave * 8;
            gl_lds16(A + (size_t)(m0 + rbase + srow) * HIDDEN + k0 + schunk * 8,
                     &Alds[rbase * 64]);
        }
#pragma unroll
        for (int p = 0; p < 2; p++) {
            int rbase = p * 32 + wave * 8;
            gl_lds16(Bt + (size_t)(n0 + rbase + srow) * HIDDEN + k0 + schunk * 8,
                     &Blds[rbase * 64]);
        }
        __syncthreads();
        short8 aF[4][2], bF[2][2];
#pragma unroll
        for (int h = 0; h < 2; h++) {
#pragma unroll
            for (int i = 0; i < 4; i++) {
                int row = wr * 64 + i * 16 + l15;
                aF[i][h] = *(const short8*)(&Alds[row * 64 + ((h * 4 + quad) ^ (l15 & 7)) * 8]);
            }
#pragma unroll
            for (int j = 0; j < 2; j++) {
                int row = wc * 32 + j * 16 + l15;
                bF[j][h] = *(const short8*)(&Blds[row * 64 + ((h * 4 + quad) ^ (l15 & 7)) * 8]);
            }
        }
#pragma unroll
        for (int h = 0; h < 2; h++)
#pragma unroll
            for (int i = 0; i < 4; i++)
#pragma unroll
                for (int j = 0; j < 2; j++)
                    acc[i][j] = mfma16(aF[i][h], bF[j][h], acc[i][j]);
        __syncthreads();
    }

#pragma unroll
    for (int i = 0; i < 4; i++) {
        int mbase = m0 + wr * 64 + i * 16 + quad * 4;
#pragma unroll
        for (int j = 0; j < 2; j++) {
            int n = n0 + wc * 32 + j * 16 + l15;
#pragma unroll
            for (int r = 0; r < 4; r++)
                Out[(size_t)(mbase + r) * HIDDEN + n] = acc[i][j][r];
        }
    }
}

// ---------------------------------------------------------------- V shift + transpose (mod pre-folded in gemm)
// Vpt[bh][d][s] = (Vm[s][d] + Vm[(s+1)%S][d])/sqrt2. grid = (bh=32, stile=32).
__global__ __launch_bounds__(256) void vshift_kernel(const unsigned short* __restrict__ Vm,
                                                     unsigned short* __restrict__ Vpt) {
    __shared__ unsigned short lds[65][72];
    int bh = blockIdx.x, b = bh >> 4, h = bh & 15;
    int s0 = blockIdx.y * 64;
    int t = threadIdx.x;
    int cg = t & 15, r0 = t >> 4;
#pragma unroll
    for (int rr = 0; rr < 4; rr++) {
        int row = r0 + rr * 16;
        ushort4 v = *(const ushort4*)(Vm + ((size_t)(b * SEQ + s0 + row)) * HIDDEN + h * 64 + cg * 4);
        *(ushort4*)(&lds[row][cg * 4]) = v;
    }
    if (t < 16) {
        int srow = (s0 + 64) & (SEQ - 1);
        ushort4 v = *(const ushort4*)(Vm + ((size_t)(b * SEQ + srow)) * HIDDEN + h * 64 + t * 4);
        *(ushort4*)(&lds[64][t * 4]) = v;
    }
    __syncthreads();
    int d = t & 63, sb = (t >> 6) * 16;
    unsigned short outv[16];
#pragma unroll
    for (int k = 0; k < 16; k++) {
        float a = bf2f(lds[sb + k][d]), bb = bf2f(lds[sb + k + 1][d]);
        outv[k] = f2bf((a + bb) * 0.7071067811865476f);
    }
    unsigned short* dst = Vpt + ((size_t)bh * 64 + d) * SEQ + s0 + sb;
#pragma unroll
    for (int k = 0; k < 16; k += 4) {
        ushort4 o; o.x = outv[k]; o.y = outv[k+1]; o.z = outv[k+2]; o.w = outv[k+3];
        *(ushort4*)(dst + k) = o;
    }
}

// ---------------------------------------------------------------- flash attention (unchanged R12)
#define KT 64
#define PSTR 76    // P row stride: quad bank offsets {0,24,16,8} -> <=2-way
__global__ __launch_bounds__(256) void attn_kernel(const unsigned short* __restrict__ Cq,
                                                   const unsigned short* __restrict__ Ck,
                                                   const unsigned short* __restrict__ Vpt,
                                                   unsigned short* __restrict__ Ob,
                                                   const float* __restrict__ mod2,
                                                   const float* __restrict__ posc,
                                                   const float* __restrict__ poss) {
    __shared__ unsigned short Klds[2][KT * 64];      // 2 x 8 KB, unpadded
    __shared__ unsigned short Vtlds[2][64 * 64];     // 2 x 8 KB, unpadded
    __shared__ unsigned short Plds[4 * 32 * PSTR];   // 19456 B
    const int bh = blockIdx.x;
    const int b = bh >> 4, h = bh & 15;
    const int tid = threadIdx.x, wave = tid >> 6, lane = tid & 63;
    const int quad = lane >> 4, l15 = lane & 15;
    const int q0 = blockIdx.y * 128 + wave * 32;

    short8 qf[2][2];
#pragma unroll
    for (int g = 0; g < 2; g++) {
        int ss = q0 + g * 16 + l15;
        const unsigned short* crow = Cq + ((size_t)(b * SEQ + ss)) * HIDDEN + h * 64;
#pragma unroll
        for (int kk = 0; kk < 2; kk++) {
            int bd = kk * 32 + quad * 8;
            short8 u = *(const short8*)(crow + bd);
            short8 q;
#pragma unroll
            for (int e = 0; e < 8; e++)
                q[e] = (short)f2bf(bf2f((unsigned short)u[e]) * mod2[h * 64 + bd + e]);
            qf[g][kk] = q;
        }
    }
    float ci[2][4], si[2][4];
#pragma unroll
    for (int g = 0; g < 2; g++)
#pragma unroll
        for (int r = 0; r < 4; r++) {
            int ss = q0 + g * 16 + quad * 4 + r;
            ci[g][r] = posc[ss];
            si[g][r] = poss[ss];
        }

    short8 ones;
#pragma unroll
    for (int e = 0; e < 8; e++) ones[e] = (short)0x3F80;

    const f32x4 z4 = {0.f, 0.f, 0.f, 0.f};
    f32x4 acc[2][4], accden[2];
#pragma unroll
    for (int g = 0; g < 2; g++) {
#pragma unroll
        for (int dt = 0; dt < 4; dt++) acc[g][dt] = z4;
        accden[g] = z4;
    }

    unsigned short* pw = &Plds[wave * 32 * PSTR];

    const unsigned short* Kbh = Ck  + ((size_t)b * SEQ) * HIDDEN + h * 64;
    const unsigned short* Vbh = Vpt + (size_t)bh * 64 * SEQ;

    auto stage = [&](int j, int buf) {
#pragma unroll
        for (int p = 0; p < 2; p++) {
            int rb = p * 32 + wave * 8;
            int r  = rb + (lane >> 3);
            int c  = (lane & 7) ^ (r & 7);
            gl_lds16(Kbh + (size_t)(j + r) * HIDDEN + c * 8, &Klds[buf][rb * 64]);
        }
#pragma unroll
        for (int p = 0; p < 2; p++) {
            int rb = p * 32 + wave * 8;
            int r  = rb + (lane >> 3);
            int c  = (lane & 7) ^ (r & 7);
            gl_lds16(Vbh + (size_t)r * SEQ + j + c * 8, &Vtlds[buf][rb * 64]);
        }
    };

    float cjc[4], sjc[4];
#pragma unroll
    for (int t2 = 0; t2 < 4; t2++) {
        int jj = t2 * 16 + l15;
        cjc[t2] = posc[jj]; sjc[t2] = poss[jj];
    }

    stage(0, 0);
    for (int it = 0; it < SEQ / KT; it++) {
        __syncthreads();
        float cjn[4] = {0.f, 0.f, 0.f, 0.f}, sjn[4] = {0.f, 0.f, 0.f, 0.f};
        if (it + 1 < SEQ / KT) {
            stage((it + 1) * KT, (it + 1) & 1);
#pragma unroll
            for (int t2 = 0; t2 < 4; t2++) {
                int jj = (it + 1) * KT + t2 * 16 + l15;
                cjn[t2] = posc[jj]; sjn[t2] = poss[jj];
            }
        }
        const int buf = it & 1;

#pragma unroll
        for (int t2 = 0; t2 < 4; t2++) {
            float cj = cjc[t2], sj = sjc[t2];
            f32x4 sc[2] = {z4, z4};
#pragma unroll
            for (int kk = 0; kk < 2; kk++) {
                int ch = (kk * 4 + quad) ^ (l15 & 7);
                short8 kf = *(const short8*)(&Klds[buf][(t2 * 16 + l15) * 64 + ch * 8]);
#pragma unroll
                for (int g = 0; g < 2; g++)
                    sc[g] = mfma16(qf[g][kk], kf, sc[g]);
            }
#pragma unroll
            for (int g = 0; g < 2; g++) {
#pragma unroll
                for (int r = 0; r < 4; r++) {
                    float w = ci[g][r] * cj + si[g][r] * sj;
                    float p = __builtin_amdgcn_exp2f(sc[g][r] * w);
                    unsigned short pt = (unsigned short)(__builtin_bit_cast(unsigned int, p) >> 16);
                    pw[(g * 16 + quad * 4 + r) * PSTR + t2 * 16 + l15] = pt;
                }
            }
        }

#pragma unroll
        for (int pt = 0; pt < 2; pt++) {
            short8 pa0 = *(const short8*)(&pw[(l15) * PSTR + pt * 32 + quad * 8]);
            short8 pa1 = *(const short8*)(&pw[(16 + l15) * PSTR + pt * 32 + quad * 8]);
            accden[0] = mfma16(pa0, ones, accden[0]);
            accden[1] = mfma16(pa1, ones, accden[1]);
#pragma unroll
            for (int dt = 0; dt < 4; dt++) {
                int ch = (pt * 4 + quad) ^ (l15 & 7);
                short8 vb = *(const short8*)(&Vtlds[buf][(dt * 16 + l15) * 64 + ch * 8]);
                acc[0][dt] = mfma16(pa0, vb, acc[0][dt]);
                acc[1][dt] = mfma16(pa1, vb, acc[1][dt]);
            }
        }
#pragma unroll
        for (int t2 = 0; t2 < 4; t2++) { cjc[t2] = cjn[t2]; sjc[t2] = sjn[t2]; }
    }

#pragma unroll
    for (int g = 0; g < 2; g++) {
        float rinv[4];
#pragma unroll
        for (int r = 0; r < 4; r++) rinv[r] = 1.0f / accden[g][r];
#pragma unroll
        for (int dt = 0; dt < 4; dt++) {
#pragma unroll
            for (int r = 0; r < 4; r++) {
                int q = q0 + g * 16 + quad * 4 + r;
                int d = dt * 16 + l15;
                Ob[((size_t)(b * SEQ + q)) * HIDDEN + h * 64 + d] = f2bf(acc[g][dt][r] * rinv[r]);
            }
        }
    }
}

// ---------------------------------------------------------------- launch
extern "C" void kernel_launch(void* const* d_in, const int* in_sizes, int n_in,
                              void* d_out, int out_size, void* d_ws, size_t ws_size,
                              hipStream_t stream) {
    const float* x  = (const float*)d_in[0];
    const float* Wq = (const float*)d_in[1];
    const float* Wk = (const float*)d_in[2];
    const float* Wv = (const float*)d_in[3];
    const float* Wo = (const float*)d_in[4];
    const float* qp = (const float*)d_in[5];
    const float* qa = (const float*)d_in[6];
    char* ws = (char*)d_ws;

    unsigned short* Xb  = (unsigned short*)(ws);                      // 8 MB (reused as Ob)
    unsigned short* Wt  = (unsigned short*)(ws + (size_t)( 8 << 20)); // 8 MB (4 x 2MB)
    unsigned short* Cq  = (unsigned short*)(ws + (size_t)(16 << 20)); // 8 MB
    unsigned short* Ck  = (unsigned short*)(ws + (size_t)(24 << 20)); // 8 MB
    unsigned short* Cv  = (unsigned short*)(ws + (size_t)(32 << 20)); // 8 MB (holds V*mod)
    unsigned short* Vpt = (unsigned short*)(ws + (size_t)(40 << 20)); // 8 MB
    float* mod  = (float*)(ws + (size_t)(48 << 20));
    float* mod2 = mod + 1024;
    float* posc = mod2 + 1024;
    float* poss = posc + 2048;
    float* out  = (float*)d_out;

    prep_kernel<<<5120, 256, 0, stream>>>(x, Xb, Wq, Wk, Wv, Wo, Wt,
                                          qp, qa, mod, mod2, posc, poss);
    gemm_kernel<<<dim3(32, 8, 3), 256, 0, stream>>>(Xb, Wt, Cq, mod);   // -> Cq,Ck,Cv(modded)
    vshift_kernel<<<dim3(32, 32), 256, 0, stream>>>(Cv, Vpt);
    attn_kernel<<<dim3(32, 16), 256, 0, stream>>>(Cq, Ck, Vpt, Xb /*Ob*/, mod2, posc, poss);
    gemm_o_kernel<<<dim3(32, 16), 256, 0, stream>>>(Xb, Wt + (size_t)3 * HIDDEN * HIDDEN, out);
}

// Round 16
// 237.697 us; speedup vs baseline: 1.0976x; 1.0359x over previous
//
#include <hip/hip_runtime.h>
#include <hip/hip_bf16.h>
#include <math.h>

// Problem constants
#define HIDDEN 1024
#define HEADS  16
#define HDIM   64
#define BATCH  2
#define SEQ    2048
#define ROWS   (BATCH*SEQ)   // 4096
#define BH     (BATCH*HEADS) // 32

typedef __attribute__((ext_vector_type(8))) short  short8;
typedef __attribute__((ext_vector_type(8))) __bf16 bf16x8;
typedef __attribute__((ext_vector_type(4))) float  f32x4;

static __device__ __forceinline__ unsigned short f2bf(float f) {
    unsigned int u = __builtin_bit_cast(unsigned int, f);
    u += 0x7FFFu + ((u >> 16) & 1u);   // round-to-nearest-even
    return (unsigned short)(u >> 16);
}
static __device__ __forceinline__ float bf2f(unsigned short h) {
    unsigned int u = ((unsigned int)h) << 16;
    return __builtin_bit_cast(float, u);
}
static __device__ __forceinline__ f32x4 mfma16(short8 a, short8 b, f32x4 c) {
    return __builtin_amdgcn_mfma_f32_16x16x32_bf16(
        __builtin_bit_cast(bf16x8, a), __builtin_bit_cast(bf16x8, b), c, 0, 0, 0);
}
// async global->LDS, 16B per lane; lds dest = wave-uniform base + lane*16
static __device__ __forceinline__ void gl_lds16(const unsigned short* g, unsigned short* l) {
    __builtin_amdgcn_global_load_lds(
        (const __attribute__((address_space(1))) unsigned int*)g,
        (__attribute__((address_space(3))) unsigned int*)l, 16, 0, 0);
}

// ---------------------------------------------------------------- prep: x->bf16 + W->bf16^T + consts
// grid 5120: blocks [0,4096) convert x (+ mod/pos tables in first 8); [4096,5120) transpose W.
__global__ __launch_bounds__(256) void prep_kernel(
    const float* __restrict__ x, unsigned short* __restrict__ xb,
    const float* __restrict__ w0, const float* __restrict__ w1,
    const float* __restrict__ w2, const float* __restrict__ w3,
    unsigned short* __restrict__ wt,
    const float* __restrict__ qp, const float* __restrict__ qa,
    float* __restrict__ mod, float* __restrict__ mod2,
    float* __restrict__ posc, float* __restrict__ poss) {
    __shared__ unsigned short tile[64][72];
    const int bid = blockIdx.x;
    const int t = threadIdx.x;
    if (bid < 4096) {
        int i = (bid * 256 + t) * 4;
        float4 v = *(const float4*)(x + i);
        ushort4 o;
        o.x = f2bf(v.x); o.y = f2bf(v.y); o.z = f2bf(v.z); o.w = f2bf(v.w);
        *(ushort4*)(xb + i) = o;
        if (bid < 8) {
            int k = bid * 256 + t;
            if (k < HIDDEN) {
                float m = cosf(qp[k]) * qa[k];
                mod[k] = m;
                mod2[k] = m * m * 0.18033688011112042f;   // mod^2 * 0.125 * log2(e)
            }
            if (k < SEQ) {
                float ang = (float)k * (6.283185307179586f / (float)SEQ);
                posc[k] = cosf(ang);
                poss[k] = sinf(ang);
            }
        }
        return;
    }
    int rem = bid - 4096;
    int z = rem >> 8, r2 = rem & 255;
    int n0 = (r2 & 15) * 64, k0 = (r2 >> 4) * 64;
    const float* src = (z == 0) ? w0 : (z == 1) ? w1 : (z == 2) ? w2 : w3;
    unsigned short* dst = wt + (size_t)z * HIDDEN * HIDDEN;
    int cg = t & 15, r0 = t >> 4;
#pragma unroll
    for (int rr = 0; rr < 4; rr++) {
        int kl = r0 + rr * 16;
        float4 v = *(const float4*)(src + (size_t)(k0 + kl) * HIDDEN + n0 + cg * 4);
        tile[cg*4+0][kl] = f2bf(v.x);
        tile[cg*4+1][kl] = f2bf(v.y);
        tile[cg*4+2][kl] = f2bf(v.z);
        tile[cg*4+3][kl] = f2bf(v.w);
    }
    __syncthreads();
#pragma unroll
    for (int rr = 0; rr < 4; rr++) {
        int nl = r0 + rr * 16;
        ushort4 o;
        o.x = tile[nl][cg*4+0]; o.y = tile[nl][cg*4+1];
        o.z = tile[nl][cg*4+2]; o.w = tile[nl][cg*4+3];
        *(ushort4*)(dst + (size_t)(n0 + nl) * HIDDEN + k0 + cg * 4) = o;
    }
}

// ---------------------------------------------------------------- GEMM QKV (128x128, BK=64, XOR swizzle)
// mode 0/1: plain bf16 C. mode 2: C*mod (V-mod folded). grid (32,8,3): id%8 -> XCD-pinned m-panel.
__global__ __launch_bounds__(256) void gemm_kernel(
    const unsigned short* __restrict__ A, const unsigned short* __restrict__ WtBase,
    unsigned short* __restrict__ CBase, const float* __restrict__ mod) {
    __shared__ unsigned short Alds[128 * 64];   // 16 KB
    __shared__ unsigned short Blds[128 * 64];   // 16 KB
    const int mode = blockIdx.z;
    const unsigned short* Bt = WtBase + (size_t)mode * HIDDEN * HIDDEN;
    unsigned short* Cout = CBase + (size_t)mode * ROWS * HIDDEN;
    const int m0 = blockIdx.x * 128, n0 = blockIdx.y * 128;
    const int tid = threadIdx.x;
    const int wave = tid >> 6, lane = tid & 63, quad = lane >> 4, l15 = lane & 15;
    const int wr = wave >> 1, wc = wave & 1;
    const int srow = lane >> 3;
    const int schunk = (lane & 7) ^ (srow & 7);          // swizzled source chunk

    f32x4 acc[4][4];
    const f32x4 z4 = {0.f, 0.f, 0.f, 0.f};
#pragma unroll
    for (int i = 0; i < 4; i++)
#pragma unroll
        for (int j = 0; j < 4; j++) acc[i][j] = z4;

    for (int k0 = 0; k0 < HIDDEN; k0 += 64) {
#pragma unroll
        for (int p = 0; p < 4; p++) {
            int rbase = p * 32 + wave * 8;
            gl_lds16(A  + (size_t)(m0 + rbase + srow) * HIDDEN + k0 + schunk * 8,
                     &Alds[rbase * 64]);
            gl_lds16(Bt + (size_t)(n0 + rbase + srow) * HIDDEN + k0 + schunk * 8,
                     &Blds[rbase * 64]);
        }
        __syncthreads();
        short8 aF[4][2], bF[4][2];
#pragma unroll
        for (int h = 0; h < 2; h++) {
#pragma unroll
            for (int i = 0; i < 4; i++) {
                int row = wr * 64 + i * 16 + l15;
                aF[i][h] = *(const short8*)(&Alds[row * 64 + ((h * 4 + quad) ^ (l15 & 7)) * 8]);
            }
#pragma unroll
            for (int j = 0; j < 4; j++) {
                int row = wc * 64 + j * 16 + l15;
                bF[j][h] = *(const short8*)(&Blds[row * 64 + ((h * 4 + quad) ^ (l15 & 7)) * 8]);
            }
        }
#pragma unroll
        for (int h = 0; h < 2; h++)
#pragma unroll
            for (int i = 0; i < 4; i++)
#pragma unroll
                for (int j = 0; j < 4; j++)
                    acc[i][j] = mfma16(aF[i][h], bF[j][h], acc[i][j]);
        __syncthreads();
    }

#pragma unroll
    for (int i = 0; i < 4; i++) {
        int mbase = m0 + wr * 64 + i * 16 + quad * 4;
#pragma unroll
        for (int j = 0; j < 4; j++) {
            int n = n0 + wc * 64 + j * 16 + l15;
            float vm = (mode == 2) ? mod[n] : 1.0f;
#pragma unroll
            for (int r = 0; r < 4; r++) {
                int mm = mbase + r;
                Cout[(size_t)mm * HIDDEN + n] = f2bf(acc[i][j][r] * vm);
            }
        }
    }
}

// ---------------------------------------------------------------- GEMM O: 128x64 tile, BK=64
// grid (32,16) = 512 blocks = 2/CU. fp32 out. id%8 -> XCD-pinned m-panel.
__global__ __launch_bounds__(256) void gemm_o_kernel(
    const unsigned short* __restrict__ A, const unsigned short* __restrict__ Bt,
    float* __restrict__ Out) {
    __shared__ unsigned short Alds[128 * 64];   // 16 KB
    __shared__ unsigned short Blds[64 * 64];    // 8 KB
    const int m0 = blockIdx.x * 128, n0 = blockIdx.y * 64;
    const int tid = threadIdx.x;
    const int wave = tid >> 6, lane = tid & 63, quad = lane >> 4, l15 = lane & 15;
    const int wr = wave >> 1, wc = wave & 1;
    const int srow = lane >> 3;
    const int schunk = (lane & 7) ^ (srow & 7);

    f32x4 acc[4][2];
    const f32x4 z4 = {0.f, 0.f, 0.f, 0.f};
#pragma unroll
    for (int i = 0; i < 4; i++)
#pragma unroll
        for (int j = 0; j < 2; j++) acc[i][j] = z4;

    for (int k0 = 0; k0 < HIDDEN; k0 += 64) {
#pragma unroll
        for (int p = 0; p < 4; p++) {
            int rbase = p * 32 + wave * 8;
            gl_lds16(A + (size_t)(m0 + rbase + srow) * HIDDEN + k0 + schunk * 8,
                     &Alds[rbase * 64]);
        }
#pragma unroll
        for (int p = 0; p < 2; p++) {
            int rbase = p * 32 + wave * 8;
            gl_lds16(Bt + (size_t)(n0 + rbase + srow) * HIDDEN + k0 + schunk * 8,
                     &Blds[rbase * 64]);
        }
        __syncthreads();
        short8 aF[4][2], bF[2][2];
#pragma unroll
        for (int h = 0; h < 2; h++) {
#pragma unroll
            for (int i = 0; i < 4; i++) {
                int row = wr * 64 + i * 16 + l15;
                aF[i][h] = *(const short8*)(&Alds[row * 64 + ((h * 4 + quad) ^ (l15 & 7)) * 8]);
            }
#pragma unroll
            for (int j = 0; j < 2; j++) {
                int row = wc * 32 + j * 16 + l15;
                bF[j][h] = *(const short8*)(&Blds[row * 64 + ((h * 4 + quad) ^ (l15 & 7)) * 8]);
            }
        }
#pragma unroll
        for (int h = 0; h < 2; h++)
#pragma unroll
            for (int i = 0; i < 4; i++)
#pragma unroll
                for (int j = 0; j < 2; j++)
                    acc[i][j] = mfma16(aF[i][h], bF[j][h], acc[i][j]);
        __syncthreads();
    }

#pragma unroll
    for (int i = 0; i < 4; i++) {
        int mbase = m0 + wr * 64 + i * 16 + quad * 4;
#pragma unroll
        for (int j = 0; j < 2; j++) {
            int n = n0 + wc * 32 + j * 16 + l15;
#pragma unroll
            for (int r = 0; r < 4; r++)
                Out[(size_t)(mbase + r) * HIDDEN + n] = acc[i][j][r];
        }
    }
}

// ---------------------------------------------------------------- V shift + transpose (mod pre-folded in gemm)
// Vpt[bh][d][s] = (Vm[s][d] + Vm[(s+1)%S][d])/sqrt2. grid = (bh=32, stile=32).
__global__ __launch_bounds__(256) void vshift_kernel(const unsigned short* __restrict__ Vm,
                                                     unsigned short* __restrict__ Vpt) {
    __shared__ unsigned short lds[65][72];
    int bh = blockIdx.x, b = bh >> 4, h = bh & 15;
    int s0 = blockIdx.y * 64;
    int t = threadIdx.x;
    int cg = t & 15, r0 = t >> 4;
#pragma unroll
    for (int rr = 0; rr < 4; rr++) {
        int row = r0 + rr * 16;
        ushort4 v = *(const ushort4*)(Vm + ((size_t)(b * SEQ + s0 + row)) * HIDDEN + h * 64 + cg * 4);
        *(ushort4*)(&lds[row][cg * 4]) = v;
    }
    if (t < 16) {
        int srow = (s0 + 64) & (SEQ - 1);
        ushort4 v = *(const ushort4*)(Vm + ((size_t)(b * SEQ + srow)) * HIDDEN + h * 64 + t * 4);
        *(ushort4*)(&lds[64][t * 4]) = v;
    }
    __syncthreads();
    int d = t & 63, sb = (t >> 6) * 16;
    unsigned short outv[16];
#pragma unroll
    for (int k = 0; k < 16; k++) {
        float a = bf2f(lds[sb + k][d]), bb = bf2f(lds[sb + k + 1][d]);
        outv[k] = f2bf((a + bb) * 0.7071067811865476f);
    }
    unsigned short* dst = Vpt + ((size_t)bh * 64 + d) * SEQ + s0 + sb;
#pragma unroll
    for (int k = 0; k < 16; k += 4) {
        ushort4 o; o.x = outv[k]; o.y = outv[k+1]; o.z = outv[k+2]; o.w = outv[k+3];
        *(ushort4*)(dst + k) = o;
    }
}

// ---------------------------------------------------------------- flash attention (KT=128: half the barriers)
// D=64 QK + scalar interference; MFMA denominator (ones-B); double-buffered KT=128 tiles
// (16 iters, 1 barrier each). P chunked at 32 keys ([32q][32k], PSTR2=44, conflict-free,
// wave-private in-order DS -> no barrier between reuse). kf shared across q-groups.
// LDS 75 KB -> 2 blocks/CU. grid (bh=32, qtile=16); bh fast -> per-XCD K/V L2 residency.
#define KT 128
#define PSTR2 44   // P row stride (32+12 shorts): quad offsets {0,24,16,8}, reads 22*l15 distinct
__global__ __launch_bounds__(256) void attn_kernel(const unsigned short* __restrict__ Cq,
                                                   const unsigned short* __restrict__ Ck,
                                                   const unsigned short* __restrict__ Vpt,
                                                   unsigned short* __restrict__ Ob,
                                                   const float* __restrict__ mod2,
                                                   const float* __restrict__ posc,
                                                   const float* __restrict__ poss) {
    __shared__ unsigned short Klds[2][KT * 64];      // 2 x 16 KB, unpadded
    __shared__ unsigned short Vtlds[2][64 * 128];    // 2 x 16 KB, unpadded
    __shared__ unsigned short Plds[4 * 32 * PSTR2];  // 11264 B
    const int bh = blockIdx.x;
    const int b = bh >> 4, h = bh & 15;
    const int tid = threadIdx.x, wave = tid >> 6, lane = tid & 63;
    const int quad = lane >> 4, l15 = lane & 15;
    const int q0 = blockIdx.y * 128 + wave * 32;

    // Q fragments (D=64): q'_d = Cq_d * mod2_d
    short8 qf[2][2];
#pragma unroll
    for (int g = 0; g < 2; g++) {
        int ss = q0 + g * 16 + l15;
        const unsigned short* crow = Cq + ((size_t)(b * SEQ + ss)) * HIDDEN + h * 64;
#pragma unroll
        for (int kk = 0; kk < 2; kk++) {
            int bd = kk * 32 + quad * 8;
            short8 u = *(const short8*)(crow + bd);
            short8 q;
#pragma unroll
            for (int e = 0; e < 8; e++)
                q[e] = (short)f2bf(bf2f((unsigned short)u[e]) * mod2[h * 64 + bd + e]);
            qf[g][kk] = q;
        }
    }
    float ci[2][4], si[2][4];
#pragma unroll
    for (int g = 0; g < 2; g++)
#pragma unroll
        for (int r = 0; r < 4; r++) {
            int ss = q0 + g * 16 + quad * 4 + r;
            ci[g][r] = posc[ss];
            si[g][r] = poss[ss];
        }

    short8 ones;
#pragma unroll
    for (int e = 0; e < 8; e++) ones[e] = (short)0x3F80;

    const f32x4 z4 = {0.f, 0.f, 0.f, 0.f};
    f32x4 acc[2][4], accden[2];
#pragma unroll
    for (int g = 0; g < 2; g++) {
#pragma unroll
        for (int dt = 0; dt < 4; dt++) acc[g][dt] = z4;
        accden[g] = z4;
    }

    unsigned short* pw = &Plds[wave * 32 * PSTR2];

    const unsigned short* Kbh = Ck  + ((size_t)b * SEQ) * HIDDEN + h * 64;   // row stride HIDDEN
    const unsigned short* Vbh = Vpt + (size_t)bh * 64 * SEQ;                 // row stride SEQ

    // stage one 128-key tile (K: 128x64, V^T: 64x128), async, XOR-swizzled
    auto stage = [&](int j, int buf) {
#pragma unroll
        for (int p = 0; p < 4; p++) {               // K: 128 rows, 8 rows/instr/wave
            int rb = p * 32 + wave * 8;
            int r  = rb + (lane >> 3);
            int c  = (lane & 7) ^ (r & 7);
            gl_lds16(Kbh + (size_t)(j + r) * HIDDEN + c * 8, &Klds[buf][rb * 64]);
        }
#pragma unroll
        for (int p = 0; p < 4; p++) {               // V^T: 64 rows x 128 keys, 4 rows/instr/wave
            int rb = p * 16 + wave * 4;
            int r  = rb + (lane >> 4);
            int c  = (lane & 15) ^ (r & 15);
            gl_lds16(Vbh + (size_t)r * SEQ + j + c * 8, &Vtlds[buf][rb * 128]);
        }
    };

    // key-col interference factors for current tile (8 subtiles of 16)
    float cjc[8], sjc[8];
#pragma unroll
    for (int tt = 0; tt < 8; tt++) {
        int jj = tt * 16 + l15;
        cjc[tt] = posc[jj]; sjc[tt] = poss[jj];
    }

    stage(0, 0);
    const int NIT = SEQ / KT;   // 16
    for (int it = 0; it < NIT; it++) {
        __syncthreads();                 // drains stage(it); prev-buf reads done
        float cjn[8], sjn[8];
        if (it + 1 < NIT) {
            stage((it + 1) * KT, (it + 1) & 1);     // overlap w/ compute
#pragma unroll
            for (int tt = 0; tt < 8; tt++) {
                int jj = (it + 1) * KT + tt * 16 + l15;
                cjn[tt] = posc[jj]; sjn[tt] = poss[jj];
            }
        } else {
#pragma unroll
            for (int tt = 0; tt < 8; tt++) { cjn[tt] = 0.f; sjn[tt] = 0.f; }
        }
        const int buf = it & 1;

        // 4 chunks of 32 keys: QK (2 subtiles, kf shared across g) -> P -> PV
#pragma unroll
        for (int chunk = 0; chunk < 4; chunk++) {
#pragma unroll
            for (int t2i = 0; t2i < 2; t2i++) {
                int tt = chunk * 2 + t2i;
                float cj = cjc[tt], sj = sjc[tt];
                f32x4 sc[2] = {z4, z4};
#pragma unroll
                for (int kk = 0; kk < 2; kk++) {
                    int ch = (kk * 4 + quad) ^ (l15 & 7);
                    short8 kf = *(const short8*)(&Klds[buf][(tt * 16 + l15) * 64 + ch * 8]);
#pragma unroll
                    for (int g = 0; g < 2; g++)
                        sc[g] = mfma16(qf[g][kk], kf, sc[g]);
                }
#pragma unroll
                for (int g = 0; g < 2; g++) {
#pragma unroll
                    for (int r = 0; r < 4; r++) {
                        float w = ci[g][r] * cj + si[g][r] * sj;
                        float p = __builtin_amdgcn_exp2f(sc[g][r] * w);
                        unsigned short pt = (unsigned short)(__builtin_bit_cast(unsigned int, p) >> 16);
                        pw[(g * 16 + quad * 4 + r) * PSTR2 + t2i * 16 + l15] = pt;
                    }
                }
            }
            // PV + denominator over this 32-key chunk (wave-private P; in-order DS)
            short8 pa0 = *(const short8*)(&pw[(l15) * PSTR2 + quad * 8]);
            short8 pa1 = *(const short8*)(&pw[(16 + l15) * PSTR2 + quad * 8]);
            accden[0] = mfma16(pa0, ones, accden[0]);
            accden[1] = mfma16(pa1, ones, accden[1]);
#pragma unroll
            for (int dt = 0; dt < 4; dt++) {
                int ch = (chunk * 4 + quad) ^ l15;
                short8 vb = *(const short8*)(&Vtlds[buf][(dt * 16 + l15) * 128 + ch * 8]);
                acc[0][dt] = mfma16(pa0, vb, acc[0][dt]);
                acc[1][dt] = mfma16(pa1, vb, acc[1][dt]);
            }
        }
#pragma unroll
        for (int tt = 0; tt < 8; tt++) { cjc[tt] = cjn[tt]; sjc[tt] = sjn[tt]; }
    }

#pragma unroll
    for (int g = 0; g < 2; g++) {
        float rinv[4];
#pragma unroll
        for (int r = 0; r < 4; r++) rinv[r] = 1.0f / accden[g][r];
#pragma unroll
        for (int dt = 0; dt < 4; dt++) {
#pragma unroll
            for (int r = 0; r < 4; r++) {
                int q = q0 + g * 16 + quad * 4 + r;
                int d = dt * 16 + l15;
                Ob[((size_t)(b * SEQ + q)) * HIDDEN + h * 64 + d] = f2bf(acc[g][dt][r] * rinv[r]);
            }
        }
    }
}

// ---------------------------------------------------------------- launch
extern "C" void kernel_launch(void* const* d_in, const int* in_sizes, int n_in,
                              void* d_out, int out_size, void* d_ws, size_t ws_size,
                              hipStream_t stream) {
    const float* x  = (const float*)d_in[0];
    const float* Wq = (const float*)d_in[1];
    const float* Wk = (const float*)d_in[2];
    const float* Wv = (const float*)d_in[3];
    const float* Wo = (const float*)d_in[4];
    const float* qp = (const float*)d_in[5];
    const float* qa = (const float*)d_in[6];
    char* ws = (char*)d_ws;

    unsigned short* Xb  = (unsigned short*)(ws);                      // 8 MB (reused as Ob)
    unsigned short* Wt  = (unsigned short*)(ws + (size_t)( 8 << 20)); // 8 MB (4 x 2MB)
    unsigned short* Cq  = (unsigned short*)(ws + (size_t)(16 << 20)); // 8 MB
    unsigned short* Ck  = (unsigned short*)(ws + (size_t)(24 << 20)); // 8 MB
    unsigned short* Cv  = (unsigned short*)(ws + (size_t)(32 << 20)); // 8 MB (holds V*mod)
    unsigned short* Vpt = (unsigned short*)(ws + (size_t)(40 << 20)); // 8 MB
    float* mod  = (float*)(ws + (size_t)(48 << 20));
    float* mod2 = mod + 1024;
    float* posc = mod2 + 1024;
    float* poss = posc + 2048;
    float* out  = (float*)d_out;

    prep_kernel<<<5120, 256, 0, stream>>>(x, Xb, Wq, Wk, Wv, Wo, Wt,
                                          qp, qa, mod, mod2, posc, poss);
    gemm_kernel<<<dim3(32, 8, 3), 256, 0, stream>>>(Xb, Wt, Cq, mod);   // -> Cq,Ck,Cv(modded)
    vshift_kernel<<<dim3(32, 32), 256, 0, stream>>>(Cv, Vpt);
    attn_kernel<<<dim3(32, 16), 256, 0, stream>>>(Cq, Ck, Vpt, Xb /*Ob*/, mod2, posc, poss);
    gemm_o_kernel<<<dim3(32, 16), 256, 0, stream>>>(Xb, Wt + (size_t)3 * HIDDEN * HIDDEN, out);
}

// Round 17
// 230.525 us; speedup vs baseline: 1.1318x; 1.0311x over previous
//
#include <hip/hip_runtime.h>
#include <hip/hip_bf16.h>
#include <math.h>

// Problem constants
#define HIDDEN 1024
#define HEADS  16
#define HDIM   64
#define BATCH  2
#define SEQ    2048
#define ROWS   (BATCH*SEQ)   // 4096
#define BH     (BATCH*HEADS) // 32

typedef __attribute__((ext_vector_type(8))) short  short8;
typedef __attribute__((ext_vector_type(8))) __bf16 bf16x8;
typedef __attribute__((ext_vector_type(4))) float  f32x4;

static __device__ __forceinline__ unsigned short f2bf(float f) {
    unsigned int u = __builtin_bit_cast(unsigned int, f);
    u += 0x7FFFu + ((u >> 16) & 1u);   // round-to-nearest-even
    return (unsigned short)(u >> 16);
}
static __device__ __forceinline__ float bf2f(unsigned short h) {
    unsigned int u = ((unsigned int)h) << 16;
    return __builtin_bit_cast(float, u);
}
static __device__ __forceinline__ f32x4 mfma16(short8 a, short8 b, f32x4 c) {
    return __builtin_amdgcn_mfma_f32_16x16x32_bf16(
        __builtin_bit_cast(bf16x8, a), __builtin_bit_cast(bf16x8, b), c, 0, 0, 0);
}
// async global->LDS, 16B per lane; lds dest = wave-uniform base + lane*16
static __device__ __forceinline__ void gl_lds16(const unsigned short* g, unsigned short* l) {
    __builtin_amdgcn_global_load_lds(
        (const __attribute__((address_space(1))) unsigned int*)g,
        (__attribute__((address_space(3))) unsigned int*)l, 16, 0, 0);
}

// ---------------------------------------------------------------- prep: x->bf16 + W->bf16^T + consts
// grid 5120: blocks [0,4096) convert x (+ mod/pos tables in first 8); [4096,5120) transpose W.
__global__ __launch_bounds__(256) void prep_kernel(
    const float* __restrict__ x, unsigned short* __restrict__ xb,
    const float* __restrict__ w0, const float* __restrict__ w1,
    const float* __restrict__ w2, const float* __restrict__ w3,
    unsigned short* __restrict__ wt,
    const float* __restrict__ qp, const float* __restrict__ qa,
    float* __restrict__ mod, float* __restrict__ mod2,
    float* __restrict__ posc, float* __restrict__ poss) {
    __shared__ unsigned short tile[64][72];
    const int bid = blockIdx.x;
    const int t = threadIdx.x;
    if (bid < 4096) {
        int i = (bid * 256 + t) * 4;
        float4 v = *(const float4*)(x + i);
        ushort4 o;
        o.x = f2bf(v.x); o.y = f2bf(v.y); o.z = f2bf(v.z); o.w = f2bf(v.w);
        *(ushort4*)(xb + i) = o;
        if (bid < 8) {
            int k = bid * 256 + t;
            if (k < HIDDEN) {
                float m = cosf(qp[k]) * qa[k];
                mod[k] = m;
                mod2[k] = m * m * 0.18033688011112042f;   // mod^2 * 0.125 * log2(e)
            }
            if (k < SEQ) {
                float ang = (float)k * (6.283185307179586f / (float)SEQ);
                posc[k] = cosf(ang);
                poss[k] = sinf(ang);
            }
        }
        return;
    }
    int rem = bid - 4096;
    int z = rem >> 8, r2 = rem & 255;
    int n0 = (r2 & 15) * 64, k0 = (r2 >> 4) * 64;
    const float* src = (z == 0) ? w0 : (z == 1) ? w1 : (z == 2) ? w2 : w3;
    unsigned short* dst = wt + (size_t)z * HIDDEN * HIDDEN;
    int cg = t & 15, r0 = t >> 4;
#pragma unroll
    for (int rr = 0; rr < 4; rr++) {
        int kl = r0 + rr * 16;
        float4 v = *(const float4*)(src + (size_t)(k0 + kl) * HIDDEN + n0 + cg * 4);
        tile[cg*4+0][kl] = f2bf(v.x);
        tile[cg*4+1][kl] = f2bf(v.y);
        tile[cg*4+2][kl] = f2bf(v.z);
        tile[cg*4+3][kl] = f2bf(v.w);
    }
    __syncthreads();
#pragma unroll
    for (int rr = 0; rr < 4; rr++) {
        int nl = r0 + rr * 16;
        ushort4 o;
        o.x = tile[nl][cg*4+0]; o.y = tile[nl][cg*4+1];
        o.z = tile[nl][cg*4+2]; o.w = tile[nl][cg*4+3];
        *(ushort4*)(dst + (size_t)(n0 + nl) * HIDDEN + k0 + cg * 4) = o;
    }
}

// ---------------------------------------------------------------- GEMM QKV: 128x64 tile, BK=64
// grid (32,16,3) = 1536 blocks = 6/CU dispatched (LDS 24 KB). mode 0/1: plain bf16 C;
// mode 2: C*mod (V-mod folded). id%8 -> XCD-pinned m-panel.
__global__ __launch_bounds__(256) void gemm_kernel(
    const unsigned short* __restrict__ A, const unsigned short* __restrict__ WtBase,
    unsigned short* __restrict__ CBase, const float* __restrict__ mod) {
    __shared__ unsigned short Alds[128 * 64];   // 16 KB
    __shared__ unsigned short Blds[64 * 64];    // 8 KB
    const int mode = blockIdx.z;
    const unsigned short* Bt = WtBase + (size_t)mode * HIDDEN * HIDDEN;
    unsigned short* Cout = CBase + (size_t)mode * ROWS * HIDDEN;
    const int m0 = blockIdx.x * 128, n0 = blockIdx.y * 64;
    const int tid = threadIdx.x;
    const int wave = tid >> 6, lane = tid & 63, quad = lane >> 4, l15 = lane & 15;
    const int wr = wave >> 1, wc = wave & 1;
    const int srow = lane >> 3;
    const int schunk = (lane & 7) ^ (srow & 7);

    f32x4 acc[4][2];
    const f32x4 z4 = {0.f, 0.f, 0.f, 0.f};
#pragma unroll
    for (int i = 0; i < 4; i++)
#pragma unroll
        for (int j = 0; j < 2; j++) acc[i][j] = z4;

    for (int k0 = 0; k0 < HIDDEN; k0 += 64) {
#pragma unroll
        for (int p = 0; p < 4; p++) {
            int rbase = p * 32 + wave * 8;
            gl_lds16(A + (size_t)(m0 + rbase + srow) * HIDDEN + k0 + schunk * 8,
                     &Alds[rbase * 64]);
        }
#pragma unroll
        for (int p = 0; p < 2; p++) {
            int rbase = p * 32 + wave * 8;
            gl_lds16(Bt + (size_t)(n0 + rbase + srow) * HIDDEN + k0 + schunk * 8,
                     &Blds[rbase * 64]);
        }
        __syncthreads();
        short8 aF[4][2], bF[2][2];
#pragma unroll
        for (int h = 0; h < 2; h++) {
#pragma unroll
            for (int i = 0; i < 4; i++) {
                int row = wr * 64 + i * 16 + l15;
                aF[i][h] = *(const short8*)(&Alds[row * 64 + ((h * 4 + quad) ^ (l15 & 7)) * 8]);
            }
#pragma unroll
            for (int j = 0; j < 2; j++) {
                int row = wc * 32 + j * 16 + l15;
                bF[j][h] = *(const short8*)(&Blds[row * 64 + ((h * 4 + quad) ^ (l15 & 7)) * 8]);
            }
        }
#pragma unroll
        for (int h = 0; h < 2; h++)
#pragma unroll
            for (int i = 0; i < 4; i++)
#pragma unroll
                for (int j = 0; j < 2; j++)
                    acc[i][j] = mfma16(aF[i][h], bF[j][h], acc[i][j]);
        __syncthreads();
    }

#pragma unroll
    for (int i = 0; i < 4; i++) {
        int mbase = m0 + wr * 64 + i * 16 + quad * 4;
#pragma unroll
        for (int j = 0; j < 2; j++) {
            int n = n0 + wc * 32 + j * 16 + l15;
            float vm = (mode == 2) ? mod[n] : 1.0f;
#pragma unroll
            for (int r = 0; r < 4; r++) {
                int mm = mbase + r;
                Cout[(size_t)mm * HIDDEN + n] = f2bf(acc[i][j][r] * vm);
            }
        }
    }
}

// ---------------------------------------------------------------- GEMM O: 128x64 tile, BK=64
// grid (32,16) = 512 blocks = 2/CU. fp32 out. id%8 -> XCD-pinned m-panel.
__global__ __launch_bounds__(256) void gemm_o_kernel(
    const unsigned short* __restrict__ A, const unsigned short* __restrict__ Bt,
    float* __restrict__ Out) {
    __shared__ unsigned short Alds[128 * 64];   // 16 KB
    __shared__ unsigned short Blds[64 * 64];    // 8 KB
    const int m0 = blockIdx.x * 128, n0 = blockIdx.y * 64;
    const int tid = threadIdx.x;
    const int wave = tid >> 6, lane = tid & 63, quad = lane >> 4, l15 = lane & 15;
    const int wr = wave >> 1, wc = wave & 1;
    const int srow = lane >> 3;
    const int schunk = (lane & 7) ^ (srow & 7);

    f32x4 acc[4][2];
    const f32x4 z4 = {0.f, 0.f, 0.f, 0.f};
#pragma unroll
    for (int i = 0; i < 4; i++)
#pragma unroll
        for (int j = 0; j < 2; j++) acc[i][j] = z4;

    for (int k0 = 0; k0 < HIDDEN; k0 += 64) {
#pragma unroll
        for (int p = 0; p < 4; p++) {
            int rbase = p * 32 + wave * 8;
            gl_lds16(A + (size_t)(m0 + rbase + srow) * HIDDEN + k0 + schunk * 8,
                     &Alds[rbase * 64]);
        }
#pragma unroll
        for (int p = 0; p < 2; p++) {
            int rbase = p * 32 + wave * 8;
            gl_lds16(Bt + (size_t)(n0 + rbase + srow) * HIDDEN + k0 + schunk * 8,
                     &Blds[rbase * 64]);
        }
        __syncthreads();
        short8 aF[4][2], bF[2][2];
#pragma unroll
        for (int h = 0; h < 2; h++) {
#pragma unroll
            for (int i = 0; i < 4; i++) {
                int row = wr * 64 + i * 16 + l15;
                aF[i][h] = *(const short8*)(&Alds[row * 64 + ((h * 4 + quad) ^ (l15 & 7)) * 8]);
            }
#pragma unroll
            for (int j = 0; j < 2; j++) {
                int row = wc * 32 + j * 16 + l15;
                bF[j][h] = *(const short8*)(&Blds[row * 64 + ((h * 4 + quad) ^ (l15 & 7)) * 8]);
            }
        }
#pragma unroll
        for (int h = 0; h < 2; h++)
#pragma unroll
            for (int i = 0; i < 4; i++)
#pragma unroll
                for (int j = 0; j < 2; j++)
                    acc[i][j] = mfma16(aF[i][h], bF[j][h], acc[i][j]);
        __syncthreads();
    }

#pragma unroll
    for (int i = 0; i < 4; i++) {
        int mbase = m0 + wr * 64 + i * 16 + quad * 4;
#pragma unroll
        for (int j = 0; j < 2; j++) {
            int n = n0 + wc * 32 + j * 16 + l15;
#pragma unroll
            for (int r = 0; r < 4; r++)
                Out[(size_t)(mbase + r) * HIDDEN + n] = acc[i][j][r];
        }
    }
}

// ---------------------------------------------------------------- V shift + transpose (mod pre-folded in gemm)
// Vpt[bh][d][s] = (Vm[s][d] + Vm[(s+1)%S][d])/sqrt2. grid = (bh=32, stile=32).
__global__ __launch_bounds__(256) void vshift_kernel(const unsigned short* __restrict__ Vm,
                                                     unsigned short* __restrict__ Vpt) {
    __shared__ unsigned short lds[65][72];
    int bh = blockIdx.x, b = bh >> 4, h = bh & 15;
    int s0 = blockIdx.y * 64;
    int t = threadIdx.x;
    int cg = t & 15, r0 = t >> 4;
#pragma unroll
    for (int rr = 0; rr < 4; rr++) {
        int row = r0 + rr * 16;
        ushort4 v = *(const ushort4*)(Vm + ((size_t)(b * SEQ + s0 + row)) * HIDDEN + h * 64 + cg * 4);
        *(ushort4*)(&lds[row][cg * 4]) = v;
    }
    if (t < 16) {
        int srow = (s0 + 64) & (SEQ - 1);
        ushort4 v = *(const ushort4*)(Vm + ((size_t)(b * SEQ + srow)) * HIDDEN + h * 64 + t * 4);
        *(ushort4*)(&lds[64][t * 4]) = v;
    }
    __syncthreads();
    int d = t & 63, sb = (t >> 6) * 16;
    unsigned short outv[16];
#pragma unroll
    for (int k = 0; k < 16; k++) {
        float a = bf2f(lds[sb + k][d]), bb = bf2f(lds[sb + k + 1][d]);
        outv[k] = f2bf((a + bb) * 0.7071067811865476f);
    }
    unsigned short* dst = Vpt + ((size_t)bh * 64 + d) * SEQ + s0 + sb;
#pragma unroll
    for (int k = 0; k < 16; k += 4) {
        ushort4 o; o.x = outv[k]; o.y = outv[k+1]; o.z = outv[k+2]; o.w = outv[k+3];
        *(ushort4*)(dst + k) = o;
    }
}

// ---------------------------------------------------------------- flash attention (KT=128, unchanged R15)
#define KT 128
#define PSTR2 44   // P row stride (32+12 shorts): quad offsets {0,24,16,8}, reads 22*l15 distinct
__global__ __launch_bounds__(256) void attn_kernel(const unsigned short* __restrict__ Cq,
                                                   const unsigned short* __restrict__ Ck,
                                                   const unsigned short* __restrict__ Vpt,
                                                   unsigned short* __restrict__ Ob,
                                                   const float* __restrict__ mod2,
                                                   const float* __restrict__ posc,
                                                   const float* __restrict__ poss) {
    __shared__ unsigned short Klds[2][KT * 64];      // 2 x 16 KB, unpadded
    __shared__ unsigned short Vtlds[2][64 * 128];    // 2 x 16 KB, unpadded
    __shared__ unsigned short Plds[4 * 32 * PSTR2];  // 11264 B
    const int bh = blockIdx.x;
    const int b = bh >> 4, h = bh & 15;
    const int tid = threadIdx.x, wave = tid >> 6, lane = tid & 63;
    const int quad = lane >> 4, l15 = lane & 15;
    const int q0 = blockIdx.y * 128 + wave * 32;

    short8 qf[2][2];
#pragma unroll
    for (int g = 0; g < 2; g++) {
        int ss = q0 + g * 16 + l15;
        const unsigned short* crow = Cq + ((size_t)(b * SEQ + ss)) * HIDDEN + h * 64;
#pragma unroll
        for (int kk = 0; kk < 2; kk++) {
            int bd = kk * 32 + quad * 8;
            short8 u = *(const short8*)(crow + bd);
            short8 q;
#pragma unroll
            for (int e = 0; e < 8; e++)
                q[e] = (short)f2bf(bf2f((unsigned short)u[e]) * mod2[h * 64 + bd + e]);
            qf[g][kk] = q;
        }
    }
    float ci[2][4], si[2][4];
#pragma unroll
    for (int g = 0; g < 2; g++)
#pragma unroll
        for (int r = 0; r < 4; r++) {
            int ss = q0 + g * 16 + quad * 4 + r;
            ci[g][r] = posc[ss];
            si[g][r] = poss[ss];
        }

    short8 ones;
#pragma unroll
    for (int e = 0; e < 8; e++) ones[e] = (short)0x3F80;

    const f32x4 z4 = {0.f, 0.f, 0.f, 0.f};
    f32x4 acc[2][4], accden[2];
#pragma unroll
    for (int g = 0; g < 2; g++) {
#pragma unroll
        for (int dt = 0; dt < 4; dt++) acc[g][dt] = z4;
        accden[g] = z4;
    }

    unsigned short* pw = &Plds[wave * 32 * PSTR2];

    const unsigned short* Kbh = Ck  + ((size_t)b * SEQ) * HIDDEN + h * 64;   // row stride HIDDEN
    const unsigned short* Vbh = Vpt + (size_t)bh * 64 * SEQ;                 // row stride SEQ

    auto stage = [&](int j, int buf) {
#pragma unroll
        for (int p = 0; p < 4; p++) {               // K: 128 rows, 8 rows/instr/wave
            int rb = p * 32 + wave * 8;
            int r  = rb + (lane >> 3);
            int c  = (lane & 7) ^ (r & 7);
            gl_lds16(Kbh + (size_t)(j + r) * HIDDEN + c * 8, &Klds[buf][rb * 64]);
        }
#pragma unroll
        for (int p = 0; p < 4; p++) {               // V^T: 64 rows x 128 keys, 4 rows/instr/wave
            int rb = p * 16 + wave * 4;
            int r  = rb + (lane >> 4);
            int c  = (lane & 15) ^ (r & 15);
            gl_lds16(Vbh + (size_t)r * SEQ + j + c * 8, &Vtlds[buf][rb * 128]);
        }
    };

    float cjc[8], sjc[8];
#pragma unroll
    for (int tt = 0; tt < 8; tt++) {
        int jj = tt * 16 + l15;
        cjc[tt] = posc[jj]; sjc[tt] = poss[jj];
    }

    stage(0, 0);
    const int NIT = SEQ / KT;   // 16
    for (int it = 0; it < NIT; it++) {
        __syncthreads();                 // drains stage(it); prev-buf reads done
        float cjn[8], sjn[8];
        if (it + 1 < NIT) {
            stage((it + 1) * KT, (it + 1) & 1);     // overlap w/ compute
#pragma unroll
            for (int tt = 0; tt < 8; tt++) {
                int jj = (it + 1) * KT + tt * 16 + l15;
                cjn[tt] = posc[jj]; sjn[tt] = poss[jj];
            }
        } else {
#pragma unroll
            for (int tt = 0; tt < 8; tt++) { cjn[tt] = 0.f; sjn[tt] = 0.f; }
        }
        const int buf = it & 1;

        // 4 chunks of 32 keys: QK (2 subtiles, kf shared across g) -> P -> PV
#pragma unroll
        for (int chunk = 0; chunk < 4; chunk++) {
#pragma unroll
            for (int t2i = 0; t2i < 2; t2i++) {
                int tt = chunk * 2 + t2i;
                float cj = cjc[tt], sj = sjc[tt];
                f32x4 sc[2] = {z4, z4};
#pragma unroll
                for (int kk = 0; kk < 2; kk++) {
                    int ch = (kk * 4 + quad) ^ (l15 & 7);
                    short8 kf = *(const short8*)(&Klds[buf][(tt * 16 + l15) * 64 + ch * 8]);
#pragma unroll
                    for (int g = 0; g < 2; g++)
                        sc[g] = mfma16(qf[g][kk], kf, sc[g]);
                }
#pragma unroll
                for (int g = 0; g < 2; g++) {
#pragma unroll
                    for (int r = 0; r < 4; r++) {
                        float w = ci[g][r] * cj + si[g][r] * sj;
                        float p = __builtin_amdgcn_exp2f(sc[g][r] * w);
                        unsigned short pt = (unsigned short)(__builtin_bit_cast(unsigned int, p) >> 16);
                        pw[(g * 16 + quad * 4 + r) * PSTR2 + t2i * 16 + l15] = pt;
                    }
                }
            }
            // PV + denominator over this 32-key chunk (wave-private P; in-order DS)
            short8 pa0 = *(const short8*)(&pw[(l15) * PSTR2 + quad * 8]);
            short8 pa1 = *(const short8*)(&pw[(16 + l15) * PSTR2 + quad * 8]);
            accden[0] = mfma16(pa0, ones, accden[0]);
            accden[1] = mfma16(pa1, ones, accden[1]);
#pragma unroll
            for (int dt = 0; dt < 4; dt++) {
                int ch = (chunk * 4 + quad) ^ l15;
                short8 vb = *(const short8*)(&Vtlds[buf][(dt * 16 + l15) * 128 + ch * 8]);
                acc[0][dt] = mfma16(pa0, vb, acc[0][dt]);
                acc[1][dt] = mfma16(pa1, vb, acc[1][dt]);
            }
        }
#pragma unroll
        for (int tt = 0; tt < 8; tt++) { cjc[tt] = cjn[tt]; sjc[tt] = sjn[tt]; }
    }

#pragma unroll
    for (int g = 0; g < 2; g++) {
        float rinv[4];
#pragma unroll
        for (int r = 0; r < 4; r++) rinv[r] = 1.0f / accden[g][r];
#pragma unroll
        for (int dt = 0; dt < 4; dt++) {
#pragma unroll
            for (int r = 0; r < 4; r++) {
                int q = q0 + g * 16 + quad * 4 + r;
                int d = dt * 16 + l15;
                Ob[((size_t)(b * SEQ + q)) * HIDDEN + h * 64 + d] = f2bf(acc[g][dt][r] * rinv[r]);
            }
        }
    }
}

// ---------------------------------------------------------------- launch
extern "C" void kernel_launch(void* const* d_in, const int* in_sizes, int n_in,
                              void* d_out, int out_size, void* d_ws, size_t ws_size,
                              hipStream_t stream) {
    const float* x  = (const float*)d_in[0];
    const float* Wq = (const float*)d_in[1];
    const float* Wk = (const float*)d_in[2];
    const float* Wv = (const float*)d_in[3];
    const float* Wo = (const float*)d_in[4];
    const float* qp = (const float*)d_in[5];
    const float* qa = (const float*)d_in[6];
    char* ws = (char*)d_ws;

    unsigned short* Xb  = (unsigned short*)(ws);                      // 8 MB (reused as Ob)
    unsigned short* Wt  = (unsigned short*)(ws + (size_t)( 8 << 20)); // 8 MB (4 x 2MB)
    unsigned short* Cq  = (unsigned short*)(ws + (size_t)(16 << 20)); // 8 MB
    unsigned short* Ck  = (unsigned short*)(ws + (size_t)(24 << 20)); // 8 MB
    unsigned short* Cv  = (unsigned short*)(ws + (size_t)(32 << 20)); // 8 MB (holds V*mod)
    unsigned short* Vpt = (unsigned short*)(ws + (size_t)(40 << 20)); // 8 MB
    float* mod  = (float*)(ws + (size_t)(48 << 20));
    float* mod2 = mod + 1024;
    float* posc = mod2 + 1024;
    float* poss = posc + 2048;
    float* out  = (float*)d_out;

    prep_kernel<<<5120, 256, 0, stream>>>(x, Xb, Wq, Wk, Wv, Wo, Wt,
                                          qp, qa, mod, mod2, posc, poss);
    gemm_kernel<<<dim3(32, 16, 3), 256, 0, stream>>>(Xb, Wt, Cq, mod);  // -> Cq,Ck,Cv(modded)
    vshift_kernel<<<dim3(32, 32), 256, 0, stream>>>(Cv, Vpt);
    attn_kernel<<<dim3(32, 16), 256, 0, stream>>>(Cq, Ck, Vpt, Xb /*Ob*/, mod2, posc, poss);
    gemm_o_kernel<<<dim3(32, 16), 256, 0, stream>>>(Xb, Wt + (size_t)3 * HIDDEN * HIDDEN, out);
}